// Round 12
// baseline (388.440 us; speedup 1.0000x reference)
//
#include <hip/hip_runtime.h>

#define NPTS 4096
#define NB 4
#define NROWS (NB*NPTS)       // 16384
#define EPSV 1e-5f
#define THR 1.067f            // d2 cutoff: sim==+0.0 exactly for d2>1.0667 (h^2 underflow)
#define C2 (-72.134752f)      // -50*log2(e); sim = (2^(C2*d))^2 = exp(-100 d)
#define DSCALE 61900.0f       // d in [0,1.0333) -> u16 (max 63958)
#define DINV (1.0f/61900.0f)
#define CDQ (C2*DINV)         // exp2 arg per d_q count
#define PHCOLS 2048           // columns staged per fill phase
#define JCAP 1024             // phase jbuf cap (max row degree ~985, validated R11)

typedef unsigned short u16;
typedef unsigned int u32;
typedef unsigned long long ull;

__device__ __forceinline__ float quad_d2(float4 a, float4 g) {
    float cr = fmaf(a.z, g.z, fmaf(a.y, g.y, a.x * g.x));
    return fmaf(-2.0f, cr, a.w + g.w);  // pinned FMA pattern, identical everywhere
}

// ---------------- fill: packs from raw inputs, also inits u/v ---------------
// grid 2048 x block 1024: [0,1024) dir A->B, [1024,2048) dir B->A.
// 16 rows/block, 1 row/wave; 2-phase 32KB tile + 32KB jbuf -> 2 blocks/CU.
__global__ __launch_bounds__(1024) void fill_kernel(
        const float* __restrict__ pred, const float* __restrict__ gt,
        u32* __restrict__ ee, int* __restrict__ cnt,
        float* __restrict__ u, float* __restrict__ v, int rcapLog) {
    __shared__ float4 tile[PHCOLS];              // 32 KB
    __shared__ u16 jbuf[16 * JCAP];              // 32 KB
    int tid = threadIdx.x, wave = tid >> 6, lane = tid & 63;
    int bid = blockIdx.x;
    int dir = bid >> 10;
    int rbase = (bid & 1023) * 16;
    int r = rbase + wave;                        // this wave's row
    int b = rbase >> 12;
    const float* RowRaw = dir ? gt : pred;
    const float* ColRaw = dir ? pred : gt;
    int rd = dir * NROWS + r;
    float ax = RowRaw[3*r], ay = RowRaw[3*r+1], az = RowRaw[3*r+2];
    float4 a = make_float4(ax, ay, az, (ax*ax + ay*ay) + az*az);
    int rcap = 1 << rcapLog;
    u32 outbase = (u32)rd << rcapLog;
    int o = 0;
    u16* jb = jbuf + wave * JCAP;
    for (int phase = 0; phase < NPTS / PHCOLS; ++phase) {
        __syncthreads();                         // prior epilogue done w/ tile
        {   // stage 2 cols/thread straight from raw (x,y,z) -> float4(+norm)
            int g0 = b*NPTS + phase*PHCOLS + tid;
            float x = ColRaw[3*g0], y = ColRaw[3*g0+1], z = ColRaw[3*g0+2];
            tile[tid] = make_float4(x, y, z, (x*x + y*y) + z*z);
            int g1 = g0 + 1024;
            x = ColRaw[3*g1]; y = ColRaw[3*g1+1]; z = ColRaw[3*g1+2];
            tile[tid + 1024] = make_float4(x, y, z, (x*x + y*y) + z*z);
        }
        __syncthreads();
        // scan: ballot-compacted phase-local j into wave-private jbuf
        int pc = 0;
        #pragma unroll 4
        for (int jt = 0; jt < PHCOLS; jt += 64) {
            float4 g = tile[jt + lane];
            bool keep = quad_d2(a, g) < THR;
            ull m = __ballot(keep);
            if (keep) {
                int pre = __builtin_amdgcn_mbcnt_hi((unsigned)(m >> 32),
                           __builtin_amdgcn_mbcnt_lo((unsigned)m, 0));
                jb[pc + pre] = (u16)(jt + lane); // no cap check: degree<=985<1024
            }
            pc += __popcll(m);
        }
        if (pc > JCAP) pc = JCAP;                // scalar safety clamp
        // epilogue: dense 64-lane pack+store while tile is resident
        for (int t = lane; t < pc; t += 64) {
            int jl = jb[t];
            float4 g = tile[jl];
            float d2 = quad_d2(a, g);
            float d = __builtin_amdgcn_sqrtf(fmaxf(d2, 0.0f));
            u32 dq = (u32)fmaf(d, DSCALE, 0.5f);
            ee[outbase + (o + t)] = (dq << 16) | (u32)(phase * PHCOLS + jl);
        }
        o += pc;
    }
    if (o > rcap) o = rcap;
    if (lane == 0) cnt[rd] = o;
    if (tid < 16) {                              // init u/v (replaces init_kernel)
        int rr = rbase + tid;
        if (dir == 0) u[rr] = 1.0f; else v[rr] = 1.0f;
    }
}

// ---------------- Sinkhorn half-iteration: 256 lanes per row ----------------
// target[r] = target[r] / (target[r] * sum_j sim(r,j)*source[j] + eps)
// grid 1024 x block 256, 16 rows/block processed cooperatively (balance).
__global__ __launch_bounds__(256) void pass_kernel(
        const int* __restrict__ cnt, int dir, const u32* __restrict__ ee,
        float* __restrict__ target, const float* __restrict__ source, int rcapLog) {
    __shared__ float ss[NPTS];                   // 16 KB
    __shared__ float wred[2][4];
    int tid = threadIdx.x;
    int rowBase = blockIdx.x * 16;
    int b = rowBase >> 12;
    #pragma unroll
    for (int k = 0; k < 4; ++k)
        ((float4*)ss)[tid + k*256] = ((const float4*)(source + b*NPTS))[tid + k*256];
    __syncthreads();
    int wave = tid >> 6, lane = tid & 63;
    for (int rr = 0; rr < 16; ++rr) {
        int r = rowBase + rr;                    // uniform
        int rd = dir * NROWS + r;
        int n = cnt[rd];
        u32 base = (u32)rd << rcapLog;
        float ac0 = 0.f, ac1 = 0.f;
        int t = tid;
        for (; t + 256 < n; t += 512) {          // 2-way MLP, 256-lane stride
            u32 e0 = ee[base+t], e1 = ee[base+t+256];
            float h0 = __builtin_amdgcn_exp2f((float)(e0 >> 16) * CDQ);
            float h1 = __builtin_amdgcn_exp2f((float)(e1 >> 16) * CDQ);
            ac0 = fmaf(h0 * h0, ss[e0 & 0xFFFF], ac0);
            ac1 = fmaf(h1 * h1, ss[e1 & 0xFFFF], ac1);
        }
        if (t < n) {
            u32 e0 = ee[base+t];
            float h0 = __builtin_amdgcn_exp2f((float)(e0 >> 16) * CDQ);
            ac0 = fmaf(h0 * h0, ss[e0 & 0xFFFF], ac0);
        }
        float acc = ac0 + ac1;
        #pragma unroll
        for (int off = 32; off > 0; off >>= 1) acc += __shfl_xor(acc, off);
        if (lane == 0) wred[rr & 1][wave] = acc;
        __syncthreads();                         // parity buffer: one sync/row
        if (tid == 0) {
            float s = (wred[rr&1][0] + wred[rr&1][1]) + (wred[rr&1][2] + wred[rr&1][3]);
            float to = target[r];
            target[r] = to / fmaf(to, s, EPSV);
        }
    }
}

// ---------------- final: 256 lanes per row, two-stage tournament ------------
__global__ __launch_bounds__(256) void final_kernel(
        const int* __restrict__ cnt, const u32* __restrict__ ee,
        const float* __restrict__ u, const float* __restrict__ v,
        float* __restrict__ partial, int rcapLog) {
    __shared__ float vs[NPTS];                   // 16 KB
    __shared__ float qbuf[2][4][5], dbuf[2][4][5];
    int tid = threadIdx.x;
    int rowBase = blockIdx.x * 16;               // grid 1024
    int b = rowBase >> 12;
    #pragma unroll
    for (int k = 0; k < 4; ++k)
        ((float4*)vs)[tid + k*256] = ((const float4*)(v + b*NPTS))[tid + k*256];
    __syncthreads();
    int wave = tid >> 6, lane = tid & 63;
    float wsum = 0.0f;                           // accumulated on wave 0
    for (int rr = 0; rr < 16; ++rr) {
        int r = rowBase + rr;
        int n = cnt[r];                          // dir-A rows
        u32 base = (u32)r << rcapLog;
        int par = rr & 1;
        float q0=-1.f,q1=-1.f,q2=-1.f,q3=-1.f,q4=-1.f;
        float d0=0.f,d1=0.f,d2v=0.f,d3=0.f,d4=0.f;
        for (int t = tid; t < n; t += 256) {
            u32 ea = ee[base + t];
            float fdq = (float)(ea >> 16);
            float h = __builtin_amdgcn_exp2f(fdq * CDQ);
            float q = (h * h) * vs[ea & 0xFFFF];
            if (q > q4) {                        // pure-VALU insert
                float dv = fdq * DINV;
                q4 = q; d4 = dv;
                if (q4 > q3) { float t1=q3;q3=q4;q4=t1; float t2=d3;d3=d4;d4=t2; }
                if (q3 > q2) { float t1=q2;q2=q3;q3=t1; float t2=d2v;d2v=d3;d3=t2; }
                if (q2 > q1) { float t1=q1;q1=q2;q2=t1; float t2=d1;d1=d2v;d2v=t2; }
                if (q1 > q0) { float t1=q0;q0=q1;q1=t1; float t2=d0;d0=d1;d1=t2; }
            }
        }
        // stage 1: per-wave top-5 via tournament -> LDS
        #pragma unroll
        for (int k = 0; k < 5; ++k) {
            float mq = q0, md = d0;
            #pragma unroll
            for (int off = 1; off < 64; off <<= 1) {
                float oq = __shfl_xor(mq, off), od = __shfl_xor(md, off);
                if (oq > mq) { mq = oq; md = od; }
            }
            ull ball = __ballot(q0 == mq);
            int winner = __ffsll(ball) - 1;
            if (lane == winner) {
                q0=q1; d0=d1; q1=q2; d1=d2v; q2=q3; d2v=d3; q3=q4; d3=d4;
                q4=-1.f; d4=0.f;
            }
            if (lane == 0) { qbuf[par][wave][k] = mq; dbuf[par][wave][k] = md; }
        }
        __syncthreads();                         // parity: one sync per row
        // stage 2: wave 0 merges 4x5 candidates
        if (wave == 0) {
            int w = lane / 5, k = lane - w * 5;
            bool valid = lane < 20;
            float cq = valid ? qbuf[par][w][k] : -1.f;
            float cd = valid ? dbuf[par][w][k] : 0.f;
            float S0 = 0.f, S1 = 0.f;
            #pragma unroll
            for (int k2 = 0; k2 < 5; ++k2) {
                float mq = cq, md = cd;
                #pragma unroll
                for (int off = 1; off < 64; off <<= 1) {
                    float oq = __shfl_xor(mq, off), od = __shfl_xor(md, off);
                    if (oq > mq) { mq = oq; md = od; }
                }
                if (mq > 0.0f) { S0 += mq; S1 = fmaf(mq, md, S1); }
                ull ball = __ballot(cq == mq);
                int winner = __ffsll(ball) - 1;
                if (lane == winner) cq = -1.f;
            }
            float uo = u[r];
            wsum += (uo * S1) / fmaf(uo, S0, EPSV);  // uniform across wave 0
        }
    }
    if (tid == 0) partial[blockIdx.x] = wsum;
}

// ---------------- reduce: 1024 partials -> out[0] ---------------------------
__global__ void reduce_kernel(const float* __restrict__ partial,
                              float* __restrict__ out) {
    __shared__ float ws[4];
    int tid = threadIdx.x;                       // 1 block, 256 threads
    float s = ((partial[tid] + partial[tid+256]) +
               (partial[tid+512] + partial[tid+768]));
    #pragma unroll
    for (int off = 32; off > 0; off >>= 1) s += __shfl_xor(s, off);
    if ((tid & 63) == 0) ws[tid >> 6] = s;
    __syncthreads();
    if (tid == 0) out[0] = (((ws[0] + ws[1]) + ws[2]) + ws[3]) * (1.0f / NB);
}

extern "C" void kernel_launch(void* const* d_in, const int* in_sizes, int n_in,
                              void* d_out, int out_size, void* d_ws, size_t ws_size,
                              hipStream_t stream) {
    (void)in_sizes; (void)n_in; (void)out_size;
    const float* pred = (const float*)d_in[0];
    const float* gt   = (const float*)d_in[1];
    char* p = (char*)d_ws;

    float*  u       = (float*)p;    p += 65536;
    float*  v       = (float*)p;    p += 65536;
    int*    cnt     = (int*)p;      p += 131072;             // 32768 ints
    float*  partial = (float*)p;    p += 4096;               // 1024 floats
    u32*    ee      = (u32*)p;
    size_t fixed    = (size_t)(p - (char*)d_ws);
    // exact CSR rcap=1024 (128 MB) — fits (validated R10/R11: absmax=4).
    int rcapLog = (ws_size >= fixed + (size_t)2*NROWS*1024*4) ? 10 : 9;
    float* out = (float*)d_out;

    hipLaunchKernelGGL(fill_kernel, dim3(2048), dim3(1024), 0, stream,
                       pred, gt, ee, cnt, u, v, rcapLog);
    for (int it = 0; it < 5; ++it) {
        hipLaunchKernelGGL(pass_kernel, dim3(1024), dim3(256), 0, stream,
                           cnt, 0, ee, u, v, rcapLog);   // row: u <- f(u; v)
        hipLaunchKernelGGL(pass_kernel, dim3(1024), dim3(256), 0, stream,
                           cnt, 1, ee, v, u, rcapLog);   // col: v <- f(v; u)
    }
    hipLaunchKernelGGL(final_kernel, dim3(1024), dim3(256), 0, stream,
                       cnt, ee, u, v, partial, rcapLog);
    hipLaunchKernelGGL(reduce_kernel, dim3(1), dim3(256), 0, stream, partial, out);
}

// Round 13
// 225.174 us; speedup vs baseline: 1.7251x; 1.7251x over previous
//
#include <hip/hip_runtime.h>

#define NPTS 4096
#define NB 4
#define NROWS (NB*NPTS)       // 16384
#define EPSV 1e-5f
#define THR 1.067f            // d2 cutoff: sim==+0.0 exactly for d2>1.0667 (h^2 underflow)
#define C2 (-72.134752f)      // -50*log2(e); sim = (2^(C2*d))^2 = exp(-100 d)
#define DSCALE 61900.0f       // d in [0,1.0333) -> u16 (max 63958)
#define DINV (1.0f/61900.0f)
#define CDQ (C2*DINV)         // exp2 arg per d_q count
#define PHCOLS 2048           // columns staged per fill phase
#define JCAP 1024             // phase jbuf cap (max row degree ~985, validated R11)

typedef unsigned short u16;
typedef unsigned int u32;
typedef unsigned long long ull;

__device__ __forceinline__ float quad_d2(float4 a, float4 g) {
    float cr = fmaf(a.z, g.z, fmaf(a.y, g.y, a.x * g.x));
    return fmaf(-2.0f, cr, a.w + g.w);  // pinned FMA pattern, identical everywhere
}

// ---------------- fill: packs from raw inputs, also inits u/v ---------------
// grid 2048 x block 1024: [0,1024) dir A->B, [1024,2048) dir B->A.
// 16 rows/block, 1 row/wave; 2-phase 32KB tile + 32KB jbuf -> 2 blocks/CU.
__global__ __launch_bounds__(1024) void fill_kernel(
        const float* __restrict__ pred, const float* __restrict__ gt,
        u32* __restrict__ ee, int* __restrict__ cnt,
        float* __restrict__ u, float* __restrict__ v, int rcapLog) {
    __shared__ float4 tile[PHCOLS];              // 32 KB
    __shared__ u16 jbuf[16 * JCAP];              // 32 KB
    int tid = threadIdx.x, wave = tid >> 6, lane = tid & 63;
    int bid = blockIdx.x;
    int dir = bid >> 10;
    int rbase = (bid & 1023) * 16;
    int r = rbase + wave;                        // this wave's row
    int b = rbase >> 12;
    const float* RowRaw = dir ? gt : pred;
    const float* ColRaw = dir ? pred : gt;
    int rd = dir * NROWS + r;
    float ax = RowRaw[3*r], ay = RowRaw[3*r+1], az = RowRaw[3*r+2];
    float4 a = make_float4(ax, ay, az, (ax*ax + ay*ay) + az*az);
    int rcap = 1 << rcapLog;
    u32 outbase = (u32)rd << rcapLog;
    int o = 0;
    u16* jb = jbuf + wave * JCAP;
    for (int phase = 0; phase < NPTS / PHCOLS; ++phase) {
        __syncthreads();                         // prior epilogue done w/ tile
        {   // stage 2 cols/thread straight from raw (x,y,z) -> float4(+norm)
            int g0 = b*NPTS + phase*PHCOLS + tid;
            float x = ColRaw[3*g0], y = ColRaw[3*g0+1], z = ColRaw[3*g0+2];
            tile[tid] = make_float4(x, y, z, (x*x + y*y) + z*z);
            int g1 = g0 + 1024;
            x = ColRaw[3*g1]; y = ColRaw[3*g1+1]; z = ColRaw[3*g1+2];
            tile[tid + 1024] = make_float4(x, y, z, (x*x + y*y) + z*z);
        }
        __syncthreads();
        // scan: ballot-compacted phase-local j into wave-private jbuf
        int pc = 0;
        #pragma unroll 4
        for (int jt = 0; jt < PHCOLS; jt += 64) {
            float4 g = tile[jt + lane];
            bool keep = quad_d2(a, g) < THR;
            ull m = __ballot(keep);
            if (keep) {
                int pre = __builtin_amdgcn_mbcnt_hi((unsigned)(m >> 32),
                           __builtin_amdgcn_mbcnt_lo((unsigned)m, 0));
                jb[pc + pre] = (u16)(jt + lane); // no cap check: degree<=985<1024
            }
            pc += __popcll(m);
        }
        if (pc > JCAP) pc = JCAP;                // scalar safety clamp
        // epilogue: dense 64-lane pack+store while tile is resident
        for (int t = lane; t < pc; t += 64) {
            int jl = jb[t];
            float4 g = tile[jl];
            float d2 = quad_d2(a, g);
            float d = __builtin_amdgcn_sqrtf(fmaxf(d2, 0.0f));
            u32 dq = (u32)fmaf(d, DSCALE, 0.5f);
            ee[outbase + (o + t)] = (dq << 16) | (u32)(phase * PHCOLS + jl);
        }
        o += pc;
    }
    if (o > rcap) o = rcap;
    if (lane == 0) cnt[rd] = o;
    if (tid < 16) {                              // init u/v (replaces init_kernel)
        int rr = rbase + tid;
        if (dir == 0) u[rr] = 1.0f; else v[rr] = 1.0f;
    }
}

// ---------------- Sinkhorn half-iteration: wave-per-row, no barriers --------
// target[r] = target[r] / (target[r] * sum_j sim(r,j)*source[j] + eps)
// grid 2048 x block 256: 8 rows/block, 2 rows/wave; 8 blocks/CU = 32 waves/CU.
__global__ __launch_bounds__(256) void pass_kernel(
        const int* __restrict__ cnt, int dir, const u32* __restrict__ ee,
        float* __restrict__ target, const float* __restrict__ source, int rcapLog) {
    __shared__ float ss[NPTS];                   // 16 KB
    int tid = threadIdx.x;
    int rowBase = blockIdx.x * 8;
    int b = rowBase >> 12;
    #pragma unroll
    for (int k = 0; k < 4; ++k)
        ((float4*)ss)[tid + k*256] = ((const float4*)(source + b*NPTS))[tid + k*256];
    __syncthreads();
    int wave = tid >> 6, lane = tid & 63;
    for (int rr = 0; rr < 2; ++rr) {
        int r = __builtin_amdgcn_readfirstlane(rowBase + wave*2 + rr);
        int rd = dir * NROWS + r;
        int n = cnt[rd];
        u32 base = (u32)rd << rcapLog;
        float ac0 = 0.f, ac1 = 0.f, ac2 = 0.f, ac3 = 0.f;
        int t = lane;
        for (; t + 192 < n; t += 256) {          // 4-way MLP
            u32 e0 = ee[base+t], e1 = ee[base+t+64], e2 = ee[base+t+128], e3 = ee[base+t+192];
            float h0 = __builtin_amdgcn_exp2f((float)(e0 >> 16) * CDQ);
            float h1 = __builtin_amdgcn_exp2f((float)(e1 >> 16) * CDQ);
            float h2 = __builtin_amdgcn_exp2f((float)(e2 >> 16) * CDQ);
            float h3 = __builtin_amdgcn_exp2f((float)(e3 >> 16) * CDQ);
            ac0 = fmaf(h0 * h0, ss[e0 & 0xFFFF], ac0);
            ac1 = fmaf(h1 * h1, ss[e1 & 0xFFFF], ac1);
            ac2 = fmaf(h2 * h2, ss[e2 & 0xFFFF], ac2);
            ac3 = fmaf(h3 * h3, ss[e3 & 0xFFFF], ac3);
        }
        for (; t < n; t += 64) {
            u32 e0 = ee[base+t];
            float h0 = __builtin_amdgcn_exp2f((float)(e0 >> 16) * CDQ);
            ac0 = fmaf(h0 * h0, ss[e0 & 0xFFFF], ac0);
        }
        float acc = (ac0 + ac1) + (ac2 + ac3);
        #pragma unroll
        for (int off = 32; off > 0; off >>= 1) acc += __shfl_xor(acc, off);
        float to = target[r];
        float tn = to / fmaf(to, acc, EPSV);
        if (lane == 0) target[r] = tn;
    }
}

// ---------------- final: wave-per-row top-5, block partial (no atomics) -----
__global__ __launch_bounds__(256) void final_kernel(
        const int* __restrict__ cnt, const u32* __restrict__ ee,
        const float* __restrict__ u, const float* __restrict__ v,
        float* __restrict__ partial, int rcapLog) {
    __shared__ float vs[NPTS];                   // 16 KB
    __shared__ float wpart[4];
    int tid = threadIdx.x;
    int rowBase = blockIdx.x * 16;               // grid 1024
    int b = rowBase >> 12;
    #pragma unroll
    for (int k = 0; k < 4; ++k)
        ((float4*)vs)[tid + k*256] = ((const float4*)(v + b*NPTS))[tid + k*256];
    __syncthreads();
    int wave = tid >> 6, lane = tid & 63;
    float wsum = 0.0f;
    for (int rr = 0; rr < 4; ++rr) {
        int r = __builtin_amdgcn_readfirstlane(rowBase + wave*4 + rr);
        int n = cnt[r];                          // dir-A rows
        u32 base = (u32)r << rcapLog;
        float q0=-1.f,q1=-1.f,q2=-1.f,q3=-1.f,q4=-1.f;
        float d0=0.f,d1=0.f,d2v=0.f,d3=0.f,d4=0.f;
        for (int t = lane; t < n; t += 64) {
            u32 ea = ee[base + t];
            float fdq = (float)(ea >> 16);
            float h = __builtin_amdgcn_exp2f(fdq * CDQ);
            float q = (h * h) * vs[ea & 0xFFFF];
            if (q > q4) {                        // pure-VALU insert
                float dv = fdq * DINV;
                q4 = q; d4 = dv;
                if (q4 > q3) { float t1=q3;q3=q4;q4=t1; float t2=d3;d3=d4;d4=t2; }
                if (q3 > q2) { float t1=q2;q2=q3;q3=t1; float t2=d2v;d2v=d3;d3=t2; }
                if (q2 > q1) { float t1=q1;q1=q2;q2=t1; float t2=d1;d1=d2v;d2v=t2; }
                if (q1 > q0) { float t1=q0;q0=q1;q1=t1; float t2=d0;d0=d1;d1=t2; }
            }
        }
        float S0 = 0.0f, S1 = 0.0f;
        #define TOURN_ROUND                                                  \
        {                                                                    \
            float mq = q0, md = d0;                                          \
            _Pragma("unroll")                                                \
            for (int off = 1; off < 64; off <<= 1) {                         \
                float oq = __shfl_xor(mq, off), od = __shfl_xor(md, off);    \
                if (oq > mq) { mq = oq; md = od; }                           \
            }                                                                \
            if (mq > 0.0f) { S0 += mq; S1 = fmaf(mq, md, S1); }              \
            ull ball = __ballot(q0 == mq);                                   \
            int winner = __ffsll(ball) - 1;                                  \
            if (lane == winner) {                                            \
                q0=q1; d0=d1; q1=q2; d1=d2v; q2=q3; d2v=d3; q3=q4; d3=d4;    \
                q4=-1.f; d4=0.f;                                             \
            }                                                                \
        }
        TOURN_ROUND TOURN_ROUND TOURN_ROUND TOURN_ROUND TOURN_ROUND
        #undef TOURN_ROUND
        float uo = u[r];
        wsum += (uo * S1) / fmaf(uo, S0, EPSV);
    }
    if (lane == 0) wpart[wave] = wsum;
    __syncthreads();
    if (tid == 0)
        partial[blockIdx.x] = ((wpart[0] + wpart[1]) + wpart[2]) + wpart[3];
}

// ---------------- reduce: 1024 partials -> out[0] ---------------------------
__global__ void reduce_kernel(const float* __restrict__ partial,
                              float* __restrict__ out) {
    __shared__ float ws[4];
    int tid = threadIdx.x;                       // 1 block, 256 threads
    float s = ((partial[tid] + partial[tid+256]) +
               (partial[tid+512] + partial[tid+768]));
    #pragma unroll
    for (int off = 32; off > 0; off >>= 1) s += __shfl_xor(s, off);
    if ((tid & 63) == 0) ws[tid >> 6] = s;
    __syncthreads();
    if (tid == 0) out[0] = (((ws[0] + ws[1]) + ws[2]) + ws[3]) * (1.0f / NB);
}

extern "C" void kernel_launch(void* const* d_in, const int* in_sizes, int n_in,
                              void* d_out, int out_size, void* d_ws, size_t ws_size,
                              hipStream_t stream) {
    (void)in_sizes; (void)n_in; (void)out_size;
    const float* pred = (const float*)d_in[0];
    const float* gt   = (const float*)d_in[1];
    char* p = (char*)d_ws;

    float*  u       = (float*)p;    p += 65536;
    float*  v       = (float*)p;    p += 65536;
    int*    cnt     = (int*)p;      p += 131072;             // 32768 ints
    float*  partial = (float*)p;    p += 4096;               // 1024 floats
    u32*    ee      = (u32*)p;
    size_t fixed    = (size_t)(p - (char*)d_ws);
    // exact CSR rcap=1024 (128 MB) — fits (validated R10/R11: absmax=4).
    int rcapLog = (ws_size >= fixed + (size_t)2*NROWS*1024*4) ? 10 : 9;
    float* out = (float*)d_out;

    hipLaunchKernelGGL(fill_kernel, dim3(2048), dim3(1024), 0, stream,
                       pred, gt, ee, cnt, u, v, rcapLog);
    for (int it = 0; it < 5; ++it) {
        hipLaunchKernelGGL(pass_kernel, dim3(2048), dim3(256), 0, stream,
                           cnt, 0, ee, u, v, rcapLog);   // row: u <- f(u; v)
        hipLaunchKernelGGL(pass_kernel, dim3(2048), dim3(256), 0, stream,
                           cnt, 1, ee, v, u, rcapLog);   // col: v <- f(v; u)
    }
    hipLaunchKernelGGL(final_kernel, dim3(1024), dim3(256), 0, stream,
                       cnt, ee, u, v, partial, rcapLog);
    hipLaunchKernelGGL(reduce_kernel, dim3(1), dim3(256), 0, stream, partial, out);
}